// Round 3
// baseline (1213.179 us; speedup 1.0000x reference)
//
#include <hip/hip_runtime.h>

typedef unsigned int u32;
typedef unsigned short u16;

constexpr int BATCH = 32;
constexpr int DIM   = 256;   // input channels
constexpr int NPTS  = 512;   // 8^3
constexpr int NH    = 8;
constexpr int KD    = 16;
constexpr int DHEAD = 64;    // DH / NH
constexpr int NH_KD = 128;
constexpr int DH    = 512;

__device__ __forceinline__ float bflo(u32 u){ return __uint_as_float(u << 16); }
__device__ __forceinline__ float bfhi(u32 u){ return __uint_as_float(u & 0xffff0000u); }
__device__ __forceinline__ u32 f2bf_bits(float f){
  u32 u = __float_as_uint(f);
  return (u + 0x7fffu + ((u >> 16) & 1u)) >> 16;
}
__device__ __forceinline__ u32 pack2bf(float a, float b){
  return f2bf_bits(a) | (f2bf_bits(b) << 16);
}

// ---------------------------------------------------------------------------
// K1: qkv = scale * (W x) + bias ; x fp32 (B,256,512), W fp32 (768,256).
// Split into q (fp32, feeds dwconv), k (bf16 channel-pair packed), v (bf16).
// grid (96, 32) block 256. thread t -> n = 2t, 2t+1 ; block -> 8 outputs.
// ---------------------------------------------------------------------------
__global__ __launch_bounds__(256) void k_qkv(
    const float* __restrict__ x, const float* __restrict__ w,
    const float* __restrict__ scale, const float* __restrict__ bias,
    float* __restrict__ qf, u32* __restrict__ kp, u16* __restrict__ vb)
{
  const int t  = threadIdx.x;
  const int o0 = blockIdx.x * 8;
  const int b  = blockIdx.y;
  float acc0[8], acc1[8];
  #pragma unroll
  for (int j = 0; j < 8; j++){ acc0[j] = 0.f; acc1[j] = 0.f; }

  const float* xb = x + (size_t)b * DIM * NPTS + 2 * t;
  #pragma unroll 2
  for (int c2 = 0; c2 < DIM/2; c2++){
    float2 x0 = *(const float2*)(xb + (size_t)(2*c2)   * NPTS); // ch 2c2: n, n+1
    float2 x1 = *(const float2*)(xb + (size_t)(2*c2+1) * NPTS); // ch 2c2+1
    #pragma unroll
    for (int j = 0; j < 8; j++){
      float2 wf = *(const float2*)(w + (size_t)(o0 + j) * DIM + 2*c2);
      acc0[j] += wf.x * x0.x + wf.y * x1.x;
      acc1[j] += wf.x * x0.y + wf.y * x1.y;
    }
  }
  float r0[8], r1[8];
  #pragma unroll
  for (int j = 0; j < 8; j++){
    float sc = scale[o0+j], bi = bias[o0+j];
    r0[j] = acc0[j]*sc + bi;
    r1[j] = acc1[j]*sc + bi;
  }
  if (o0 < NH_KD){                       // q -> fp32 (feeds depthwise conv)
    float* qp = qf + ((size_t)b*NH_KD + o0)*NPTS + 2*t;
    #pragma unroll
    for (int j = 0; j < 8; j++){
      *(float2*)(qp + (size_t)j*NPTS) = make_float2(r0[j], r1[j]);
    }
  } else if (o0 < 2*NH_KD){              // k -> bf16 packed channel-pairs
    int c20 = (o0 - NH_KD) >> 1;
    #pragma unroll
    for (int jj = 0; jj < 4; jj++){
      u32* kpp = kp + ((size_t)b*64 + c20 + jj)*NPTS + 2*t;
      kpp[0] = pack2bf(r0[2*jj], r0[2*jj+1]);   // n:   (c even | c odd)
      kpp[1] = pack2bf(r1[2*jj], r1[2*jj+1]);   // n+1
    }
  } else {                               // v -> bf16
    int v0 = o0 - 2*NH_KD;
    u32* vbp = (u32*)vb;
    #pragma unroll
    for (int j = 0; j < 8; j++){
      vbp[(((size_t)b*DH + v0 + j)*NPTS + 2*t) >> 1] = pack2bf(r0[j], r1[j]);
    }
  }
}

// ---------------------------------------------------------------------------
// K2: depthwise 3x3x3 conv (pad 1) on q channels + scale/bias. All fp32.
// grid (B*128) block 512 (one thread per spatial point).
// ---------------------------------------------------------------------------
__global__ __launch_bounds__(512) void k_dw(
    const float* __restrict__ qf, const float* __restrict__ dww,
    const float* __restrict__ dws, const float* __restrict__ dwb,
    float* __restrict__ qc)
{
  const int bc = blockIdx.x;            // b*128 + ch
  const int ch = bc & 127;
  const int n  = threadIdx.x;
  const int z = n >> 6, y = (n >> 3) & 7, xx = n & 7;
  float wv[27];
  #pragma unroll
  for (int i = 0; i < 27; i++) wv[i] = dww[ch*27 + i];
  const float* qp = qf + (size_t)bc * NPTS;
  float acc = 0.f;
  #pragma unroll
  for (int dz = 0; dz < 3; dz++){
    int zz = z + dz - 1; if ((unsigned)zz > 7u) continue;
    #pragma unroll
    for (int dy = 0; dy < 3; dy++){
      int yy = y + dy - 1; if ((unsigned)yy > 7u) continue;
      #pragma unroll
      for (int dx = 0; dx < 3; dx++){
        int xw = xx + dx - 1; if ((unsigned)xw > 7u) continue;
        acc += qp[zz*64 + yy*8 + xw] * wv[dz*9 + dy*3 + dx];
      }
    }
  }
  acc = acc * dws[ch] + dwb[ch];
  qc[(size_t)bc * NPTS + n] = acc;
}

// ---------------------------------------------------------------------------
// K3: fused attention. One block per (n-tile of 64, head, batch); 4 waves,
// each wave owns 16 rows. V staged in LDS in two m-halves (32KB each pass),
// scores recomputed per half. attn-out (with relu) -> bf16 pair-packed.
// LDS: 32K (v) + 8K (p) + 16K (out transpose) = 56KB -> 2 blocks/CU.
// ---------------------------------------------------------------------------
__global__ __launch_bounds__(256) void k_attn(
    const float* __restrict__ qc, const u32* __restrict__ kp,
    const u16* __restrict__ vb, const float* __restrict__ ab,
    const int* __restrict__ bidx, u32* __restrict__ attnout)
{
  __shared__ uint2 v4[64*64];                     // [m4][d] 4 bf16 each (half of m)
  __shared__ __align__(16) float p_lds[4][512];   // per-wave softmax probs
  __shared__ float out_lds[64*64];                // [n_local][d]

  const int tile = blockIdx.x, h = blockIdx.y, b = blockIdx.z;
  const int tid = threadIdx.x, wave = tid >> 6, lane = tid & 63;
  const int n0 = tile * 64;

  const u32* kph   = kp + ((size_t)b*64 + h*8) * NPTS;        // [c2(8)][m]
  const float* qch = qc + ((size_t)b*NH_KD + h*KD) * NPTS;    // [c(16)][n]
  const u16* vbh   = vb + ((size_t)b*DH + h*DHEAD) * NPTS;    // [d(64)][m]
  const float* abh = ab + h * NPTS;

  float acc[16];
  #pragma unroll
  for (int r = 0; r < 16; r++) acc[r] = 0.f;

  for (int ph = 0; ph < 2; ph++){
    const int mbase = ph * 256;
    __syncthreads();
    // stage half of V: 64 d x 256 m
    for (int i = tid; i < 64*64; i += 256){
      int d = i & 63, m4 = i >> 6;
      v4[m4*64 + d] = *(const uint2*)(vbh + (size_t)d*NPTS + mbase + m4*4);
    }
    __syncthreads();

    #pragma unroll
    for (int rp = 0; rp < 8; rp++){
      const int nl0 = wave*16 + rp*2;
      const int nA = n0 + nl0, nB = nA + 1;
      float q0[16], q1[16];
      #pragma unroll
      for (int c = 0; c < 16; c++){
        q0[c] = qch[(size_t)c*NPTS + nA];
        q1[c] = qch[(size_t)c*NPTS + nB];
      }
      float s0[8], s1[8];
      #pragma unroll
      for (int j = 0; j < 8; j++){
        int m = j*64 + lane;
        float a0 = 0.f, a1 = 0.f;
        #pragma unroll
        for (int c2 = 0; c2 < 8; c2++){
          u32 kv = kph[(size_t)c2*NPTS + m];
          float klo = bflo(kv), khi = bfhi(kv);
          a0 += q0[2*c2] * klo + q0[2*c2+1] * khi;
          a1 += q1[2*c2] * klo + q1[2*c2+1] * khi;
        }
        int i0 = bidx[(size_t)nA*NPTS + m];
        int i1 = bidx[(size_t)nB*NPTS + m];
        s0[j] = a0 * 0.25f + abh[i0];
        s1[j] = a1 * 0.25f + abh[i1];
      }

      auto proc = [&](const float (&s)[8], int r){
        float mx = s[0];
        #pragma unroll
        for (int j = 1; j < 8; j++) mx = fmaxf(mx, s[j]);
        #pragma unroll
        for (int off = 32; off > 0; off >>= 1) mx = fmaxf(mx, __shfl_xor(mx, off, 64));
        float e[8], sum = 0.f;
        #pragma unroll
        for (int j = 0; j < 8; j++){ e[j] = __expf(s[j] - mx); sum += e[j]; }
        #pragma unroll
        for (int off = 32; off > 0; off >>= 1) sum += __shfl_xor(sum, off, 64);
        float rs = 1.0f / sum;
        #pragma unroll
        for (int j = 0; j < 8; j++) p_lds[wave][j*64 + lane] = e[j] * rs;
        float a = 0.f;
        #pragma unroll 8
        for (int m4 = 0; m4 < 64; m4++){
          uint2 vv = v4[m4*64 + lane];
          float4 pv = *(const float4*)&p_lds[wave][mbase + m4*4];
          a += pv.x * bflo(vv.x) + pv.y * bfhi(vv.x)
             + pv.z * bflo(vv.y) + pv.w * bfhi(vv.y);
        }
        acc[r] += a;
      };
      proc(s0, rp*2);
      proc(s1, rp*2 + 1);
    }
  }

  // transpose + relu -> coalesced bf16-packed global store (channel-major)
  #pragma unroll
  for (int r = 0; r < 16; r++){
    out_lds[(wave*16 + r)*64 + lane] = fmaxf(acc[r], 0.f);
  }
  __syncthreads();
  u32* aout = attnout + (((size_t)b*DH + h*DHEAD) * NPTS + n0) / 2;
  for (int i = tid; i < 64*32; i += 256){
    int ch = i >> 5, np = i & 31;
    aout[(size_t)ch*(NPTS/2) + np] =
        pack2bf(out_lds[(2*np)*64 + ch], out_lds[(2*np+1)*64 + ch]);
  }
}

// ---------------------------------------------------------------------------
// K4: proj GEMM: out[b,o,n] = scale[o] * sum_c A[b,c,n] * W[o,c] + bias[o]
// A: (B, 512, 512) bf16 pair-packed over n, W: (256, 512) fp32, out fp32.
// grid (32, 32) block 256.
// ---------------------------------------------------------------------------
__global__ __launch_bounds__(256) void k_proj(
    const u32* __restrict__ A, const float* __restrict__ w,
    const float* __restrict__ scale, const float* __restrict__ bias,
    float* __restrict__ out)
{
  const int t  = threadIdx.x;
  const int o0 = blockIdx.x * 8;
  const int b  = blockIdx.y;
  float acc0[8], acc1[8];
  #pragma unroll
  for (int j = 0; j < 8; j++){ acc0[j] = 0.f; acc1[j] = 0.f; }

  const u32* Ab = A + ((size_t)b * DH * NPTS)/2 + t;   // n pair 2t,2t+1
  #pragma unroll 2
  for (int c2 = 0; c2 < DH/2; c2++){
    u32 a0 = Ab[(size_t)(2*c2)   * (NPTS/2)];
    u32 a1 = Ab[(size_t)(2*c2+1) * (NPTS/2)];
    float a00 = bflo(a0), a01 = bfhi(a0);   // ch 2c2:   n, n+1
    float a10 = bflo(a1), a11 = bfhi(a1);   // ch 2c2+1
    #pragma unroll
    for (int j = 0; j < 8; j++){
      float2 wf = *(const float2*)(w + (size_t)(o0+j)*DH + 2*c2);
      acc0[j] += wf.x*a00 + wf.y*a10;
      acc1[j] += wf.x*a01 + wf.y*a11;
    }
  }
  #pragma unroll
  for (int j = 0; j < 8; j++){
    int o = o0 + j;
    float sc = scale[o], bi = bias[o];
    *(float2*)(out + ((size_t)b*DIM + o)*NPTS + 2*t) =
        make_float2(acc0[j]*sc + bi, acc1[j]*sc + bi);
  }
}

// ---------------------------------------------------------------------------
extern "C" void kernel_launch(void* const* d_in, const int* in_sizes, int n_in,
                              void* d_out, int out_size, void* d_ws, size_t ws_size,
                              hipStream_t stream)
{
  const float* x     = (const float*)d_in[0];
  const float* qkv_w = (const float*)d_in[1];
  const float* qkv_s = (const float*)d_in[2];
  const float* qkv_b = (const float*)d_in[3];
  const float* dw_w  = (const float*)d_in[4];
  const float* dw_s  = (const float*)d_in[5];
  const float* dw_b  = (const float*)d_in[6];
  const float* ab    = (const float*)d_in[7];
  const float* pw    = (const float*)d_in[8];
  const float* ps    = (const float*)d_in[9];
  const float* pb    = (const float*)d_in[10];
  const int* bidx    = (const int*)d_in[11];

  char* ws = (char*)d_ws;
  float* qf   = (float*)(ws);                     //  8 MB  (B,128,512) fp32
  float* qc   = (float*)(ws + (8u  << 20));       //  8 MB  (B,128,512) fp32
  u32*   kp   = (u32*)  (ws + (16u << 20));       //  4 MB  (B,64,512) bf16x2
  u16*   vb   = (u16*)  (ws + (20u << 20));       // 16 MB  (B,512,512) bf16
  u32*   attn = (u32*)  (ws + (36u << 20));       // 16 MB  (B,512,512) bf16 packed

  k_qkv <<<dim3(96, 32),   256, 0, stream>>>(x, qkv_w, qkv_s, qkv_b, qf, kp, vb);
  k_dw  <<<dim3(32*128),   512, 0, stream>>>(qf, dw_w, dw_s, dw_b, qc);
  k_attn<<<dim3(8, 8, 32), 256, 0, stream>>>(qc, kp, vb, ab, bidx, attn);
  k_proj<<<dim3(32, 32),   256, 0, stream>>>(attn, pw, ps, pb, (float*)d_out);
}

// Round 4
// 355.661 us; speedup vs baseline: 3.4111x; 3.4111x over previous
//
#include <hip/hip_runtime.h>

typedef unsigned int u32;
typedef unsigned short u16;
typedef __attribute__((ext_vector_type(8))) short bf16x8;
typedef __attribute__((ext_vector_type(4))) float f32x4;

constexpr int BATCH = 32;
constexpr int DIM   = 256;
constexpr int NPTS  = 512;
constexpr int NH    = 8;
constexpr int KD    = 16;
constexpr int DHEAD = 64;
constexpr int NH_KD = 128;
constexpr int DH    = 512;

__device__ __forceinline__ float bflo(u32 u){ return __uint_as_float(u << 16); }
__device__ __forceinline__ float bfhi(u32 u){ return __uint_as_float(u & 0xffff0000u); }
__device__ __forceinline__ u32 f2bf_bits(float f){
  u32 u = __float_as_uint(f);
  return (u + 0x7fffu + ((u >> 16) & 1u)) >> 16;
}
__device__ __forceinline__ u32 pack2bf(float a, float b){
  return f2bf_bits(a) | (f2bf_bits(b) << 16);
}

// ---------------------------------------------------------------------------
// K1: qkv = scale*(W x)+bias. q -> fp32 [b][128][512] (dwconv input),
// k -> bf16 rows kb[b][h][m][16], v -> bf16 vb[b][512][512].
// ---------------------------------------------------------------------------
__global__ __launch_bounds__(256) void k_qkv(
    const float* __restrict__ x, const float* __restrict__ w,
    const float* __restrict__ scale, const float* __restrict__ bias,
    float* __restrict__ qf, u16* __restrict__ kb, u16* __restrict__ vb)
{
  const int t  = threadIdx.x;
  const int o0 = blockIdx.x * 8;
  const int b  = blockIdx.y;
  float acc0[8], acc1[8];
  #pragma unroll
  for (int j = 0; j < 8; j++){ acc0[j] = 0.f; acc1[j] = 0.f; }

  const float* xb = x + (size_t)b * DIM * NPTS + 2 * t;
  #pragma unroll 2
  for (int c2 = 0; c2 < DIM/2; c2++){
    float2 x0 = *(const float2*)(xb + (size_t)(2*c2)   * NPTS);
    float2 x1 = *(const float2*)(xb + (size_t)(2*c2+1) * NPTS);
    #pragma unroll
    for (int j = 0; j < 8; j++){
      float2 wf = *(const float2*)(w + (size_t)(o0 + j) * DIM + 2*c2);
      acc0[j] += wf.x * x0.x + wf.y * x1.x;
      acc1[j] += wf.x * x0.y + wf.y * x1.y;
    }
  }
  float r0[8], r1[8];
  #pragma unroll
  for (int j = 0; j < 8; j++){
    float sc = scale[o0+j], bi = bias[o0+j];
    r0[j] = acc0[j]*sc + bi;
    r1[j] = acc1[j]*sc + bi;
  }
  if (o0 < NH_KD){                       // q -> fp32
    float* qp = qf + ((size_t)b*NH_KD + o0)*NPTS + 2*t;
    #pragma unroll
    for (int j = 0; j < 8; j++)
      *(float2*)(qp + (size_t)j*NPTS) = make_float2(r0[j], r1[j]);
  } else if (o0 < 2*NH_KD){              // k -> kb[b][h][m][16] bf16
    int hh = (o0 - NH_KD) >> 4;
    int c0 = (o0 - NH_KD) & 15;          // 0 or 8
    u16* kbb = kb + (((size_t)b*NH + hh) * NPTS) * 16;
    int n = 2*t;
    uint4 w0 = {pack2bf(r0[0],r0[1]), pack2bf(r0[2],r0[3]),
                pack2bf(r0[4],r0[5]), pack2bf(r0[6],r0[7])};
    uint4 w1 = {pack2bf(r1[0],r1[1]), pack2bf(r1[2],r1[3]),
                pack2bf(r1[4],r1[5]), pack2bf(r1[6],r1[7])};
    *(uint4*)(kbb + (size_t)n*16 + c0)     = w0;
    *(uint4*)(kbb + (size_t)(n+1)*16 + c0) = w1;
  } else {                               // v -> bf16 [b][dh][m]
    int v0 = o0 - 2*NH_KD;
    u32* vbp = (u32*)vb;
    #pragma unroll
    for (int j = 0; j < 8; j++)
      vbp[(((size_t)b*DH + v0 + j)*NPTS + 2*t) >> 1] = pack2bf(r0[j], r1[j]);
  }
}

// ---------------------------------------------------------------------------
// K2: depthwise 3x3x3 conv + scale/bias, scaled by 0.25 (attn scale folded),
// output qb[b][h][n][16] bf16 rows. grid (B*128) block 512.
// ---------------------------------------------------------------------------
__global__ __launch_bounds__(512) void k_dw(
    const float* __restrict__ qf, const float* __restrict__ dww,
    const float* __restrict__ dws, const float* __restrict__ dwb,
    u16* __restrict__ qb)
{
  const int bc = blockIdx.x;            // b*128 + ch
  const int b  = bc >> 7;
  const int ch = bc & 127;
  const int n  = threadIdx.x;
  const int z = n >> 6, y = (n >> 3) & 7, xx = n & 7;
  float wv[27];
  #pragma unroll
  for (int i = 0; i < 27; i++) wv[i] = dww[ch*27 + i];
  const float* qp = qf + (size_t)bc * NPTS;
  float acc = 0.f;
  #pragma unroll
  for (int dz = 0; dz < 3; dz++){
    int zz = z + dz - 1; if ((unsigned)zz > 7u) continue;
    #pragma unroll
    for (int dy = 0; dy < 3; dy++){
      int yy = y + dy - 1; if ((unsigned)yy > 7u) continue;
      #pragma unroll
      for (int dx = 0; dx < 3; dx++){
        int xw = xx + dx - 1; if ((unsigned)xw > 7u) continue;
        acc += qp[zz*64 + yy*8 + xw] * wv[dz*9 + dy*3 + dx];
      }
    }
  }
  acc = (acc * dws[ch] + dwb[ch]) * 0.25f;   // fold 1/sqrt(KD)
  int hh = ch >> 4, cc = ch & 15;
  qb[(((size_t)b*NH + hh)*NPTS + n)*16 + cc] = (u16)f2bf_bits(acc);
}

// ---------------------------------------------------------------------------
// K_bias: biasr[h][nt][mt][lane][r] fp32 in MFMA C-layout order.
// n = nt*16 + (lane>>4)*4 + r, m = mt*16 + (lane&15). 8 MB.
// grid 1024 (nt,mt), block 256 (4 h-slots x 64 lanes, 2 h iters).
// ---------------------------------------------------------------------------
__global__ __launch_bounds__(256) void k_bias(
    const float* __restrict__ ab, const int* __restrict__ bidx,
    float* __restrict__ biasr)
{
  const int blk = blockIdx.x;
  const int nt = blk >> 5, mt = blk & 31;
  const int lane = threadIdx.x & 63;
  const int h0 = threadIdx.x >> 6;
  const int cq = lane >> 4;
  const int m = mt*16 + (lane & 15);
  int idx[4];
  #pragma unroll
  for (int r = 0; r < 4; r++)
    idx[r] = bidx[(size_t)(nt*16 + cq*4 + r)*NPTS + m];
  for (int h = h0; h < NH; h += 4){
    f32x4 v;
    #pragma unroll
    for (int r = 0; r < 4; r++) v[r] = ab[h*NPTS + idx[r]];
    *(f32x4*)(biasr + (((size_t)(h*32 + nt)*32 + mt)*64 + lane)*4) = v;
  }
}

// ---------------------------------------------------------------------------
// K3: MFMA flash attention. Block = (64-row tile, h, b), 4 waves, each wave
// one 16-row n-tile. Scores: 16x16x32 bf16 MFMA with k 16..31 zero.
// Online softmax in C-layout regs; P -> LDS (bf16) -> A-frag; V staged in
// LDS in 2 m-halves, fragment-friendly padded rows. Out -> bf16 packed.
// LDS: V 64x264 u16 = 33,792 + P 4x16x136 u16 = 17,408 -> 51,200 B.
// ---------------------------------------------------------------------------
__global__ __launch_bounds__(256, 2) void k_attn(
    const u16* __restrict__ qb, const u16* __restrict__ kb,
    const u16* __restrict__ vb, const float* __restrict__ biasr,
    u32* __restrict__ attnout)
{
  __shared__ __align__(16) u16 Vlds[64*264];
  __shared__ __align__(16) u16 Plds[4*16*136];

  const int tg = blockIdx.x, h = blockIdx.y, b = blockIdx.z;
  const int tid = threadIdx.x, wave = tid >> 6, lane = tid & 63;
  const int c = lane & 15, q = lane >> 4;
  const int bh = b*NH + h;
  const int n0 = tg*64 + wave*16;

  const bf16x8 zfrag = {0,0,0,0,0,0,0,0};

  // Q A-frag: row n = n0 + c, k = q*8+j (quads 2,3 zero)
  bf16x8 aQ = zfrag;
  if (q < 2)
    aQ = *(const bf16x8*)(qb + (((size_t)bh*NPTS + n0 + c) << 4) + q*8);

  const u16* vbh = vb + ((size_t)b*DH + h*DHEAD) * NPTS;
  const u16* kbh = kb + ((size_t)bh*NPTS) * 16;
  const float* biasw = biasr + ((size_t)(h*32) + (tg*4 + wave)) * 32 * 64 * 4;

  f32x4 O0 = {0,0,0,0}, O1 = {0,0,0,0}, O2 = {0,0,0,0}, O3 = {0,0,0,0};
  f32x4 m_run = {-1e30f,-1e30f,-1e30f,-1e30f};
  f32x4 l_run = {0,0,0,0};
  u16* Pw = Plds + wave*16*136;

  for (int ph = 0; ph < 2; ph++){
    __syncthreads();
    { // stage V half: rows d, cols m = ph*256 + 0..255 (coalesced 16B/lane)
      int d0 = tid >> 5;
      int ms = (tid & 31) * 8;
      const u16* src = vbh + (size_t)d0*NPTS + ph*256 + ms;
      u16* dst = Vlds + d0*264 + ms;
      #pragma unroll
      for (int it = 0; it < 8; it++)
        *(uint4*)(dst + it*8*264) = *(const uint4*)(src + (size_t)it*8*NPTS);
    }
    __syncthreads();

    for (int cc = 0; cc < 2; cc++){
      const int chunk = ph*2 + cc;
      const int mca = chunk*128;
      // ---- scores: 8 m-tiles, acc initialized with bias ----
      f32x4 S[8];
      #pragma unroll
      for (int mt = 0; mt < 8; mt++){
        int m0 = mca + mt*16;
        bf16x8 bK = zfrag;
        if (q < 2)
          bK = *(const bf16x8*)(kbh + (((size_t)(m0 + c)) << 4) + q*8);
        f32x4 bias4 = *(const f32x4*)(biasw + ((size_t)(chunk*8 + mt)*64 + lane)*4);
        S[mt] = __builtin_amdgcn_mfma_f32_16x16x32_bf16(aQ, bK, bias4, 0, 0, 0);
      }
      // ---- online softmax ----
      f32x4 cmax = S[0];
      #pragma unroll
      for (int mt = 1; mt < 8; mt++)
        #pragma unroll
        for (int r = 0; r < 4; r++) cmax[r] = fmaxf(cmax[r], S[mt][r]);
      #pragma unroll
      for (int off = 1; off < 16; off <<= 1)
        #pragma unroll
        for (int r = 0; r < 4; r++)
          cmax[r] = fmaxf(cmax[r], __shfl_xor(cmax[r], off, 64));
      f32x4 mnew, alpha;
      #pragma unroll
      for (int r = 0; r < 4; r++){
        mnew[r]  = fmaxf(m_run[r], cmax[r]);
        alpha[r] = __expf(m_run[r] - mnew[r]);
        m_run[r] = mnew[r];
      }
      f32x4 rs = {0,0,0,0};
      #pragma unroll
      for (int mt = 0; mt < 8; mt++)
        #pragma unroll
        for (int r = 0; r < 4; r++){
          float p = __expf(S[mt][r] - mnew[r]);
          rs[r] += p;
          Pw[(q*4 + r)*136 + mt*16 + c] = (u16)f2bf_bits(p);
        }
      #pragma unroll
      for (int off = 1; off < 16; off <<= 1)
        #pragma unroll
        for (int r = 0; r < 4; r++) rs[r] += __shfl_xor(rs[r], off, 64);
      #pragma unroll
      for (int r = 0; r < 4; r++){
        l_run[r] = l_run[r]*alpha[r] + rs[r];
        O0[r] *= alpha[r]; O1[r] *= alpha[r];
        O2[r] *= alpha[r]; O3[r] *= alpha[r];
      }
      // ---- PV: 4 K-steps of 32 m, 4 d-tiles ----
      #pragma unroll
      for (int ks = 0; ks < 4; ks++){
        bf16x8 aP = *(const bf16x8*)(Pw + c*136 + ks*32 + q*8);
        int mv = cc*128 + ks*32 + q*8;
        bf16x8 b0 = *(const bf16x8*)(Vlds + (0*16 + c)*264 + mv);
        bf16x8 b1 = *(const bf16x8*)(Vlds + (1*16 + c)*264 + mv);
        bf16x8 b2 = *(const bf16x8*)(Vlds + (2*16 + c)*264 + mv);
        bf16x8 b3 = *(const bf16x8*)(Vlds + (3*16 + c)*264 + mv);
        O0 = __builtin_amdgcn_mfma_f32_16x16x32_bf16(aP, b0, O0, 0, 0, 0);
        O1 = __builtin_amdgcn_mfma_f32_16x16x32_bf16(aP, b1, O1, 0, 0, 0);
        O2 = __builtin_amdgcn_mfma_f32_16x16x32_bf16(aP, b2, O2, 0, 0, 0);
        O3 = __builtin_amdgcn_mfma_f32_16x16x32_bf16(aP, b3, O3, 0, 0, 0);
      }
    }
  }

  // ---- epilogue: 1/l, relu, transpose via wave-private LDS, bf16 store ----
  float* outl = (float*)Pw;   // 16 x 65 fp32 = 4160 B <= 4352 B region
  f32x4 inv;
  #pragma unroll
  for (int r = 0; r < 4; r++) inv[r] = 1.0f / l_run[r];
  #pragma unroll
  for (int r = 0; r < 4; r++){
    outl[(q*4+r)*65 +  0 + c] = fmaxf(O0[r]*inv[r], 0.f);
    outl[(q*4+r)*65 + 16 + c] = fmaxf(O1[r]*inv[r], 0.f);
    outl[(q*4+r)*65 + 32 + c] = fmaxf(O2[r]*inv[r], 0.f);
    outl[(q*4+r)*65 + 48 + c] = fmaxf(O3[r]*inv[r], 0.f);
  }
  u32* aout = attnout + (((size_t)b*DH + h*DHEAD)*NPTS + tg*64 + wave*16) / 2;
  for (int i = lane; i < 512; i += 64){
    int d = i >> 3, np = i & 7;
    aout[(size_t)d*(NPTS/2) + np] =
        pack2bf(outl[(2*np)*65 + d], outl[(2*np+1)*65 + d]);
  }
}

// ---------------------------------------------------------------------------
// K4: proj GEMM. A: (B,512,512) bf16 pair-packed over n, W fp32, out fp32.
// ---------------------------------------------------------------------------
__global__ __launch_bounds__(256) void k_proj(
    const u32* __restrict__ A, const float* __restrict__ w,
    const float* __restrict__ scale, const float* __restrict__ bias,
    float* __restrict__ out)
{
  const int t  = threadIdx.x;
  const int o0 = blockIdx.x * 8;
  const int b  = blockIdx.y;
  float acc0[8], acc1[8];
  #pragma unroll
  for (int j = 0; j < 8; j++){ acc0[j] = 0.f; acc1[j] = 0.f; }

  const u32* Ab = A + ((size_t)b * DH * NPTS)/2 + t;
  #pragma unroll 2
  for (int c2 = 0; c2 < DH/2; c2++){
    u32 a0 = Ab[(size_t)(2*c2)   * (NPTS/2)];
    u32 a1 = Ab[(size_t)(2*c2+1) * (NPTS/2)];
    float a00 = bflo(a0), a01 = bfhi(a0);
    float a10 = bflo(a1), a11 = bfhi(a1);
    #pragma unroll
    for (int j = 0; j < 8; j++){
      float2 wf = *(const float2*)(w + (size_t)(o0+j)*DH + 2*c2);
      acc0[j] += wf.x*a00 + wf.y*a10;
      acc1[j] += wf.x*a01 + wf.y*a11;
    }
  }
  #pragma unroll
  for (int j = 0; j < 8; j++){
    int o = o0 + j;
    float sc = scale[o], bi = bias[o];
    *(float2*)(out + ((size_t)b*DIM + o)*NPTS + 2*t) =
        make_float2(acc0[j]*sc + bi, acc1[j]*sc + bi);
  }
}

// ---------------------------------------------------------------------------
extern "C" void kernel_launch(void* const* d_in, const int* in_sizes, int n_in,
                              void* d_out, int out_size, void* d_ws, size_t ws_size,
                              hipStream_t stream)
{
  const float* x     = (const float*)d_in[0];
  const float* qkv_w = (const float*)d_in[1];
  const float* qkv_s = (const float*)d_in[2];
  const float* qkv_b = (const float*)d_in[3];
  const float* dw_w  = (const float*)d_in[4];
  const float* dw_s  = (const float*)d_in[5];
  const float* dw_b  = (const float*)d_in[6];
  const float* ab    = (const float*)d_in[7];
  const float* pw    = (const float*)d_in[8];
  const float* ps    = (const float*)d_in[9];
  const float* pb    = (const float*)d_in[10];
  const int* bidx    = (const int*)d_in[11];

  char* ws = (char*)d_ws;
  float* qf    = (float*)(ws);                  //  8 MB  (B,128,512) fp32
  u16*   qb    = (u16*)  (ws + ( 8u << 20));    //  4 MB  (B,8,512,16) bf16
  u16*   kb    = (u16*)  (ws + (12u << 20));    //  4 MB  (B,8,512,16) bf16
  u16*   vb    = (u16*)  (ws + (16u << 20));    // 16 MB  (B,512,512) bf16
  u32*   attn  = (u32*)  (ws + (32u << 20));    // 16 MB  (B,512,512) bf16 packed
  float* biasr = (float*)(ws + (48u << 20));    //  8 MB  (8,32,32,64,4) fp32

  k_qkv <<<dim3(96, 32),   256, 0, stream>>>(x, qkv_w, qkv_s, qkv_b, qf, kb, vb);
  k_dw  <<<dim3(32*128),   512, 0, stream>>>(qf, dw_w, dw_s, dw_b, qb);
  k_bias<<<dim3(1024),     256, 0, stream>>>(ab, bidx, biasr);
  k_attn<<<dim3(8, 8, 32), 256, 0, stream>>>(qb, kb, vb, biasr, attn);
  k_proj<<<dim3(32, 32),   256, 0, stream>>>(attn, pw, ps, pb, (float*)d_out);
}

// Round 5
// 250.219 us; speedup vs baseline: 4.8485x; 1.4214x over previous
//
#include <hip/hip_runtime.h>

typedef unsigned int u32;
typedef unsigned short u16;
typedef __attribute__((ext_vector_type(8))) short bf16x8;
typedef __attribute__((ext_vector_type(4))) float f32x4;

constexpr int BATCH = 32;
constexpr int DIM   = 256;
constexpr int NPTS  = 512;
constexpr int NH    = 8;
constexpr int KD    = 16;
constexpr int DHEAD = 64;
constexpr int NH_KD = 128;
constexpr int DH    = 512;

__device__ __forceinline__ float bf2f(u16 u){ return __uint_as_float(((u32)u) << 16); }
__device__ __forceinline__ u32 f2bf_bits(float f){
  u32 u = __float_as_uint(f);
  return (u + 0x7fffu + ((u >> 16) & 1u)) >> 16;
}
__device__ __forceinline__ u32 pack2bf(float a, float b){
  return f2bf_bits(a) | (f2bf_bits(b) << 16);
}

union B8 { bf16x8 v; uint2 u2[2]; };

// ---------------------------------------------------------------------------
// K0: fold scale into weights, convert to bf16.
// wqb[768][256] = qkv_w * qkv_scale ; pwb[256][512] = proj_w * proj_scale.
// 640 blocks x 256 threads, 2 elems (1 u32) each.
// ---------------------------------------------------------------------------
__global__ __launch_bounds__(256) void k_prep(
    const float* __restrict__ wq, const float* __restrict__ sq,
    const float* __restrict__ wp, const float* __restrict__ sp,
    u32* __restrict__ wqb, u32* __restrict__ pwb)
{
  int t = blockIdx.x * 256 + threadIdx.x;
  if (t < 98304){                      // 768*256/2
    int i = 2*t;
    float s = sq[i >> 8];
    wqb[t] = pack2bf(wq[i]*s, wq[i+1]*s);
  } else {
    int j = t - 98304;                 // 256*512/2
    int i = 2*j;
    float s = sp[i >> 9];
    pwb[j] = pack2bf(wp[i]*s, wp[i+1]*s);
  }
}

// ---------------------------------------------------------------------------
// K1: qkv MFMA GEMM. C[o 768][n 512] per batch, K=256.
// A = wqb (bf16, scale folded) rows [o][k]; B = x transposed to LDS [n][k].
// Grid (Mblk 6, Nblk 4, b 32), block 256 = 4 waves (2x2), wave = 64x64 tile.
// Epilogue + qkv_bias, scatter: Mblk0 -> qfb bf16, 1 -> kb rows, 2-5 -> vb.
// ---------------------------------------------------------------------------
__global__ __launch_bounds__(256) void k_qkv(
    const float* __restrict__ x, const u16* __restrict__ wqb,
    const float* __restrict__ bias,
    u16* __restrict__ qfb, u16* __restrict__ kb, u16* __restrict__ vb)
{
  __shared__ __align__(16) u16 Xl[128*36];

  const int Mblk = blockIdx.x, Nblk = blockIdx.y, b = blockIdx.z;
  const int tid = threadIdx.x, wave = tid >> 6, lane = tid & 63;
  const int wm = wave >> 1, wn = wave & 1;
  const int c = lane & 15, q = lane >> 4;
  const int Mbase = Mblk*128 + wm*64;

  f32x4 acc[4][4];
  #pragma unroll
  for (int mt = 0; mt < 4; mt++){
    f32x4 bi;
    #pragma unroll
    for (int r = 0; r < 4; r++) bi[r] = bias[Mbase + mt*16 + q*4 + r];
    #pragma unroll
    for (int nt = 0; nt < 4; nt++) acc[mt][nt] = bi;
  }

  const float* xb = x + (size_t)b*DIM*NPTS + Nblk*128;

  for (int kc8 = 0; kc8 < 8; kc8++){
    const int kc = kc8*32;
    __syncthreads();
    #pragma unroll
    for (int it = 0; it < 4; it++){
      int n2 = 2*((tid & 31) + 32*(it & 1));
      int cc = 2*((tid >> 5) + 8*(it >> 1));
      const float* xr = xb + (size_t)(kc + cc)*NPTS + n2;
      float2 A = *(const float2*)xr;
      float2 Bv = *(const float2*)(xr + NPTS);
      *(u32*)(Xl + (size_t)n2*36 + cc)     = pack2bf(A.x, Bv.x);
      *(u32*)(Xl + (size_t)(n2+1)*36 + cc) = pack2bf(A.y, Bv.y);
    }
    __syncthreads();

    bf16x8 aW[4];
    #pragma unroll
    for (int mt = 0; mt < 4; mt++)
      aW[mt] = *(const bf16x8*)(wqb + (size_t)(Mbase + mt*16 + c)*256 + kc + q*8);
    B8 bX[4];
    #pragma unroll
    for (int nt = 0; nt < 4; nt++){
      const u16* base = Xl + (size_t)(wn*64 + nt*16 + c)*36 + q*8;
      bX[nt].u2[0] = *(const uint2*)(base);
      bX[nt].u2[1] = *(const uint2*)(base + 4);
    }
    #pragma unroll
    for (int mt = 0; mt < 4; mt++)
      #pragma unroll
      for (int nt = 0; nt < 4; nt++)
        acc[mt][nt] = __builtin_amdgcn_mfma_f32_16x16x32_bf16(
            aW[mt], bX[nt].v, acc[mt][nt], 0, 0, 0);
  }

  // epilogue: scatter by Mblk
  #pragma unroll
  for (int mt = 0; mt < 4; mt++){
    const int ob = wm*64 + mt*16 + q*4;         // local row base (0..127)
    #pragma unroll
    for (int nt = 0; nt < 4; nt++){
      const int n = Nblk*128 + wn*64 + nt*16 + c;
      #pragma unroll
      for (int r = 0; r < 4; r++){
        u16 bv = (u16)f2bf_bits(acc[mt][nt][r]);
        int ol = ob + r;
        if (Mblk == 0){
          qfb[((size_t)b*NH_KD + ol)*NPTS + n] = bv;
        } else if (Mblk == 1){
          kb[(((size_t)b*NH + (ol >> 4))*NPTS + n)*16 + (ol & 15)] = bv;
        } else {
          int d = (Mblk - 2)*128 + ol;
          vb[((size_t)b*DH + d)*NPTS + n] = bv;
        }
      }
    }
  }
}

// ---------------------------------------------------------------------------
// K2: depthwise 3x3x3 conv + scale/bias, x0.25 folded, bf16 in/out.
// Output qb[b][h][n][16] rows. grid (B*128) block 512.
// ---------------------------------------------------------------------------
__global__ __launch_bounds__(512) void k_dw(
    const u16* __restrict__ qfb, const float* __restrict__ dww,
    const float* __restrict__ dws, const float* __restrict__ dwb,
    u16* __restrict__ qb)
{
  const int bc = blockIdx.x;            // b*128 + ch
  const int b  = bc >> 7;
  const int ch = bc & 127;
  const int n  = threadIdx.x;
  const int z = n >> 6, y = (n >> 3) & 7, xx = n & 7;
  float wv[27];
  #pragma unroll
  for (int i = 0; i < 27; i++) wv[i] = dww[ch*27 + i];
  const u16* qp = qfb + (size_t)bc * NPTS;
  float acc = 0.f;
  #pragma unroll
  for (int dz = 0; dz < 3; dz++){
    int zz = z + dz - 1; if ((unsigned)zz > 7u) continue;
    #pragma unroll
    for (int dy = 0; dy < 3; dy++){
      int yy = y + dy - 1; if ((unsigned)yy > 7u) continue;
      #pragma unroll
      for (int dx = 0; dx < 3; dx++){
        int xw = xx + dx - 1; if ((unsigned)xw > 7u) continue;
        acc += bf2f(qp[zz*64 + yy*8 + xw]) * wv[dz*9 + dy*3 + dx];
      }
    }
  }
  acc = (acc * dws[ch] + dwb[ch]) * 0.25f;   // fold 1/sqrt(KD)
  int hh = ch >> 4, cc = ch & 15;
  qb[(((size_t)b*NH + hh)*NPTS + n)*16 + cc] = (u16)f2bf_bits(acc);
}

// ---------------------------------------------------------------------------
// K_bias: biasr[h][nt][mt][lane][r] fp32 in MFMA C-layout order. 8 MB.
// ---------------------------------------------------------------------------
__global__ __launch_bounds__(256) void k_bias(
    const float* __restrict__ ab, const int* __restrict__ bidx,
    float* __restrict__ biasr)
{
  const int blk = blockIdx.x;
  const int nt = blk >> 5, mt = blk & 31;
  const int lane = threadIdx.x & 63;
  const int h0 = threadIdx.x >> 6;
  const int cq = lane >> 4;
  const int m = mt*16 + (lane & 15);
  int idx[4];
  #pragma unroll
  for (int r = 0; r < 4; r++)
    idx[r] = bidx[(size_t)(nt*16 + cq*4 + r)*NPTS + m];
  for (int h = h0; h < NH; h += 4){
    f32x4 v;
    #pragma unroll
    for (int r = 0; r < 4; r++) v[r] = ab[h*NPTS + idx[r]];
    *(f32x4*)(biasr + (((size_t)(h*32 + nt)*32 + mt)*64 + lane)*4) = v;
  }
}

// ---------------------------------------------------------------------------
// K3: MFMA flash attention (R4 structure). Output now attn[b][n][dh] bf16
// rows (k-contiguous for the MFMA proj GEMM).
// LDS: V 64x264 u16 = 33,792 + P 4x16x136 u16 = 17,408 -> 51,200 B.
// ---------------------------------------------------------------------------
__global__ __launch_bounds__(256, 2) void k_attn(
    const u16* __restrict__ qb, const u16* __restrict__ kb,
    const u16* __restrict__ vb, const float* __restrict__ biasr,
    u32* __restrict__ attnout)
{
  __shared__ __align__(16) u16 Vlds[64*264];
  __shared__ __align__(16) u16 Plds[4*16*136];

  const int tg = blockIdx.x, h = blockIdx.y, b = blockIdx.z;
  const int tid = threadIdx.x, wave = tid >> 6, lane = tid & 63;
  const int c = lane & 15, q = lane >> 4;
  const int bh = b*NH + h;
  const int n0 = tg*64 + wave*16;

  const bf16x8 zfrag = {0,0,0,0,0,0,0,0};

  bf16x8 aQ = zfrag;
  if (q < 2)
    aQ = *(const bf16x8*)(qb + (((size_t)bh*NPTS + n0 + c) << 4) + q*8);

  const u16* vbh = vb + ((size_t)b*DH + h*DHEAD) * NPTS;
  const u16* kbh = kb + ((size_t)bh*NPTS) * 16;
  const float* biasw = biasr + ((size_t)(h*32) + (tg*4 + wave)) * 32 * 64 * 4;

  f32x4 O0 = {0,0,0,0}, O1 = {0,0,0,0}, O2 = {0,0,0,0}, O3 = {0,0,0,0};
  f32x4 m_run = {-1e30f,-1e30f,-1e30f,-1e30f};
  f32x4 l_run = {0,0,0,0};
  u16* Pw = Plds + wave*16*136;

  for (int ph = 0; ph < 2; ph++){
    __syncthreads();
    {
      int d0 = tid >> 5;
      int ms = (tid & 31) * 8;
      const u16* src = vbh + (size_t)d0*NPTS + ph*256 + ms;
      u16* dst = Vlds + d0*264 + ms;
      #pragma unroll
      for (int it = 0; it < 8; it++)
        *(uint4*)(dst + it*8*264) = *(const uint4*)(src + (size_t)it*8*NPTS);
    }
    __syncthreads();

    for (int cc = 0; cc < 2; cc++){
      const int chunk = ph*2 + cc;
      const int mca = chunk*128;
      f32x4 S[8];
      #pragma unroll
      for (int mt = 0; mt < 8; mt++){
        int m0 = mca + mt*16;
        bf16x8 bK = zfrag;
        if (q < 2)
          bK = *(const bf16x8*)(kbh + (((size_t)(m0 + c)) << 4) + q*8);
        f32x4 bias4 = *(const f32x4*)(biasw + ((size_t)(chunk*8 + mt)*64 + lane)*4);
        S[mt] = __builtin_amdgcn_mfma_f32_16x16x32_bf16(aQ, bK, bias4, 0, 0, 0);
      }
      f32x4 cmax = S[0];
      #pragma unroll
      for (int mt = 1; mt < 8; mt++)
        #pragma unroll
        for (int r = 0; r < 4; r++) cmax[r] = fmaxf(cmax[r], S[mt][r]);
      #pragma unroll
      for (int off = 1; off < 16; off <<= 1)
        #pragma unroll
        for (int r = 0; r < 4; r++)
          cmax[r] = fmaxf(cmax[r], __shfl_xor(cmax[r], off, 64));
      f32x4 mnew, alpha;
      #pragma unroll
      for (int r = 0; r < 4; r++){
        mnew[r]  = fmaxf(m_run[r], cmax[r]);
        alpha[r] = __expf(m_run[r] - mnew[r]);
        m_run[r] = mnew[r];
      }
      f32x4 rs = {0,0,0,0};
      #pragma unroll
      for (int mt = 0; mt < 8; mt++)
        #pragma unroll
        for (int r = 0; r < 4; r++){
          float p = __expf(S[mt][r] - mnew[r]);
          rs[r] += p;
          Pw[(q*4 + r)*136 + mt*16 + c] = (u16)f2bf_bits(p);
        }
      #pragma unroll
      for (int off = 1; off < 16; off <<= 1)
        #pragma unroll
        for (int r = 0; r < 4; r++) rs[r] += __shfl_xor(rs[r], off, 64);
      #pragma unroll
      for (int r = 0; r < 4; r++){
        l_run[r] = l_run[r]*alpha[r] + rs[r];
        O0[r] *= alpha[r]; O1[r] *= alpha[r];
        O2[r] *= alpha[r]; O3[r] *= alpha[r];
      }
      #pragma unroll
      for (int ks = 0; ks < 4; ks++){
        bf16x8 aP = *(const bf16x8*)(Pw + c*136 + ks*32 + q*8);
        int mv = cc*128 + ks*32 + q*8;
        bf16x8 b0 = *(const bf16x8*)(Vlds + (0*16 + c)*264 + mv);
        bf16x8 b1 = *(const bf16x8*)(Vlds + (1*16 + c)*264 + mv);
        bf16x8 b2 = *(const bf16x8*)(Vlds + (2*16 + c)*264 + mv);
        bf16x8 b3 = *(const bf16x8*)(Vlds + (3*16 + c)*264 + mv);
        O0 = __builtin_amdgcn_mfma_f32_16x16x32_bf16(aP, b0, O0, 0, 0, 0);
        O1 = __builtin_amdgcn_mfma_f32_16x16x32_bf16(aP, b1, O1, 0, 0, 0);
        O2 = __builtin_amdgcn_mfma_f32_16x16x32_bf16(aP, b2, O2, 0, 0, 0);
        O3 = __builtin_amdgcn_mfma_f32_16x16x32_bf16(aP, b3, O3, 0, 0, 0);
      }
    }
  }

  // epilogue: 1/l, relu, transpose to [n][d] rows, bf16 store
  float* outl = (float*)Pw;   // 16 x 65 fp32 = 4160 B <= 4352 B region
  f32x4 inv;
  #pragma unroll
  for (int r = 0; r < 4; r++) inv[r] = 1.0f / l_run[r];
  #pragma unroll
  for (int r = 0; r < 4; r++){
    outl[(q*4+r)*65 +  0 + c] = fmaxf(O0[r]*inv[r], 0.f);
    outl[(q*4+r)*65 + 16 + c] = fmaxf(O1[r]*inv[r], 0.f);
    outl[(q*4+r)*65 + 32 + c] = fmaxf(O2[r]*inv[r], 0.f);
    outl[(q*4+r)*65 + 48 + c] = fmaxf(O3[r]*inv[r], 0.f);
  }
  {
    const int nl = lane >> 2, seg = lane & 3;
    u32 buf[8];
    #pragma unroll
    for (int j = 0; j < 8; j++)
      buf[j] = pack2bf(outl[nl*65 + seg*16 + 2*j], outl[nl*65 + seg*16 + 2*j + 1]);
    u32* dst = attnout + ((size_t)(b*NPTS + n0 + nl))*(DH/2) + h*32 + seg*8;
    *(uint4*)dst       = make_uint4(buf[0], buf[1], buf[2], buf[3]);
    *(uint4*)(dst + 4) = make_uint4(buf[4], buf[5], buf[6], buf[7]);
  }
}

// ---------------------------------------------------------------------------
// K4: proj MFMA GEMM. C[o 256][n 512] per b, K=512. A = pwb bf16 rows
// (scale folded), B = attn[b][n][dh] bf16 rows. No LDS. Out fp32 + bias.
// Grid (2, 4, 32), block 256 = 4 waves (2x2).
// ---------------------------------------------------------------------------
__global__ __launch_bounds__(256) void k_proj(
    const u16* __restrict__ attn, const u16* __restrict__ pwb,
    const float* __restrict__ bias, float* __restrict__ out)
{
  const int Mblk = blockIdx.x, Nblk = blockIdx.y, b = blockIdx.z;
  const int tid = threadIdx.x, wave = tid >> 6, lane = tid & 63;
  const int wm = wave >> 1, wn = wave & 1;
  const int c = lane & 15, q = lane >> 4;
  const int Mbase = Mblk*128 + wm*64;
  const int Nbase = Nblk*128 + wn*64;

  f32x4 acc[4][4];
  #pragma unroll
  for (int mt = 0; mt < 4; mt++){
    f32x4 bi;
    #pragma unroll
    for (int r = 0; r < 4; r++) bi[r] = bias[Mbase + mt*16 + q*4 + r];
    #pragma unroll
    for (int nt = 0; nt < 4; nt++) acc[mt][nt] = bi;
  }

  const u16* arow = attn + (size_t)b*NPTS*DH;

  for (int kc8 = 0; kc8 < 16; kc8++){
    const int kc = kc8*32;
    bf16x8 aW[4], bA[4];
    #pragma unroll
    for (int mt = 0; mt < 4; mt++)
      aW[mt] = *(const bf16x8*)(pwb + (size_t)(Mbase + mt*16 + c)*DH + kc + q*8);
    #pragma unroll
    for (int nt = 0; nt < 4; nt++)
      bA[nt] = *(const bf16x8*)(arow + (size_t)(Nbase + nt*16 + c)*DH + kc + q*8);
    #pragma unroll
    for (int mt = 0; mt < 4; mt++)
      #pragma unroll
      for (int nt = 0; nt < 4; nt++)
        acc[mt][nt] = __builtin_amdgcn_mfma_f32_16x16x32_bf16(
            aW[mt], bA[nt], acc[mt][nt], 0, 0, 0);
  }

  #pragma unroll
  for (int mt = 0; mt < 4; mt++){
    #pragma unroll
    for (int nt = 0; nt < 4; nt++){
      const int n = Nbase + nt*16 + c;
      #pragma unroll
      for (int r = 0; r < 4; r++){
        int o = Mbase + mt*16 + q*4 + r;
        out[((size_t)b*DIM + o)*NPTS + n] = acc[mt][nt][r];
      }
    }
  }
}

// ---------------------------------------------------------------------------
extern "C" void kernel_launch(void* const* d_in, const int* in_sizes, int n_in,
                              void* d_out, int out_size, void* d_ws, size_t ws_size,
                              hipStream_t stream)
{
  const float* x     = (const float*)d_in[0];
  const float* qkv_w = (const float*)d_in[1];
  const float* qkv_s = (const float*)d_in[2];
  const float* qkv_b = (const float*)d_in[3];
  const float* dw_w  = (const float*)d_in[4];
  const float* dw_s  = (const float*)d_in[5];
  const float* dw_b  = (const float*)d_in[6];
  const float* ab    = (const float*)d_in[7];
  const float* pw    = (const float*)d_in[8];
  const float* ps    = (const float*)d_in[9];
  const float* pb    = (const float*)d_in[10];
  const int* bidx    = (const int*)d_in[11];

  char* ws = (char*)d_ws;
  u16*   qfb   = (u16*)  (ws);                  //  4 MB (B,128,512) bf16
  u16*   qb    = (u16*)  (ws + ( 4u << 20));    //  4 MB (B,8,512,16) bf16
  u16*   kb    = (u16*)  (ws + ( 8u << 20));    //  4 MB (B,8,512,16) bf16
  u16*   vb    = (u16*)  (ws + (12u << 20));    // 16 MB (B,512,512) bf16
  u32*   attn  = (u32*)  (ws + (28u << 20));    // 16 MB (B,512,512) bf16 rows [n][dh]
  float* biasr = (float*)(ws + (44u << 20));    //  8 MB (8,32,32,64,4) fp32
  u32*   wqb   = (u32*)  (ws + (52u << 20));    // 384 KB (768,256) bf16
  u32*   pwb   = (u32*)  (ws + (53u << 20));    // 256 KB (256,512) bf16

  k_prep<<<dim3(640),      256, 0, stream>>>(qkv_w, qkv_s, pw, ps, wqb, pwb);
  k_qkv <<<dim3(6, 4, 32), 256, 0, stream>>>(x, (const u16*)wqb, qkv_b, qfb, kb, vb);
  k_dw  <<<dim3(32*128),   512, 0, stream>>>(qfb, dw_w, dw_s, dw_b, qb);
  k_bias<<<dim3(1024),     256, 0, stream>>>(ab, bidx, biasr);
  k_attn<<<dim3(8, 8, 32), 256, 0, stream>>>(qb, kb, vb, biasr, attn);
  k_proj<<<dim3(2, 4, 32), 256, 0, stream>>>((const u16*)attn, (const u16*)pwb, pb, (float*)d_out);
}